// Round 4
// baseline (772.041 us; speedup 1.0000x reference)
//
#include <hip/hip_runtime.h>

#define NG 8192
#define NC 4096
#define FG 512
#define FC 256
#define ALPHA 0.2f

typedef float f32x4 __attribute__((ext_vector_type(4)));
typedef short bf16x8 __attribute__((ext_vector_type(8)));

#define AS1C(p) ((const __attribute__((address_space(1))) void*)(p))
#define AS3(p)  ((__attribute__((address_space(3))) void*)(p))

static __device__ __forceinline__ float leakyf(float x) { return fmaxf(x, ALPHA * x); }

static __device__ __forceinline__ unsigned short f2bf(float f) {
    unsigned u = __builtin_bit_cast(unsigned, f);
    u += 0x7fffu + ((u >> 16) & 1u);          // RNE; w>=0, no NaN here
    return (unsigned short)(u >> 16);
}

static __device__ __forceinline__ float wred(float v) {
#pragma unroll
    for (int m = 1; m < 64; m <<= 1) v += __shfl_xor(v, m, 64);
    return v;
}

// ---------------- projection: h = x@W  [N,K]@[K,64], + bf16 h^T, + 5 per-node scalars
__global__ __launch_bounds__(256) void proj_kernel(
    const float* __restrict__ x, const float* __restrict__ W, int K, int N,
    float* __restrict__ h, unsigned short* __restrict__ hT,
    const float* __restrict__ aA, const float* __restrict__ aB,
    const float* __restrict__ aC, const float* __restrict__ aD,
    const float* __restrict__ aG, const float* __restrict__ bG,
    float* __restrict__ sA, float* __restrict__ sB, float* __restrict__ sC,
    float* __restrict__ sD, float* __restrict__ gam)
{
    const int wave = threadIdx.x >> 6, lane = threadIdx.x & 63;
    const int r0 = blockIdx.x * 16 + wave * 4;     // 4 rows per wave
    const float* xr = x + (size_t)r0 * K;
    float acc0 = 0.f, acc1 = 0.f, acc2 = 0.f, acc3 = 0.f;
    for (int k = 0; k < K; k += 4) {
        float4 x0 = *(const float4*)(xr + k);
        float4 x1 = *(const float4*)(xr + K + k);
        float4 x2 = *(const float4*)(xr + 2 * (size_t)K + k);
        float4 x3 = *(const float4*)(xr + 3 * (size_t)K + k);
        float w0 = W[(k + 0) * 64 + lane];
        float w1 = W[(k + 1) * 64 + lane];
        float w2 = W[(k + 2) * 64 + lane];
        float w3 = W[(k + 3) * 64 + lane];
        acc0 += x0.x * w0 + x0.y * w1 + x0.z * w2 + x0.w * w3;
        acc1 += x1.x * w0 + x1.y * w1 + x1.z * w2 + x1.w * w3;
        acc2 += x2.x * w0 + x2.y * w1 + x2.z * w2 + x2.w * w3;
        acc3 += x3.x * w0 + x3.y * w1 + x3.z * w2 + x3.w * w3;
    }
    float accs[4] = {acc0, acc1, acc2, acc3};
    unsigned short hb[4];
#pragma unroll
    for (int t = 0; t < 4; t++) {
        h[(size_t)(r0 + t) * 64 + lane] = accs[t];
        hb[t] = f2bf(accs[t]);
    }
    *(ushort4*)&hT[(size_t)lane * N + r0] = make_ushort4(hb[0], hb[1], hb[2], hb[3]);

    const float cA = aA[lane], cB = aB[lane], cC = aC[lane], cD = aD[lane], cG = aG[lane];
    const float bias = bG[0];
#pragma unroll
    for (int t = 0; t < 4; t++) {
        float vA = wred(accs[t] * cA);
        float vB = wred(accs[t] * cB);
        float vC = wred(accs[t] * cC);
        float vD = wred(accs[t] * cD);
        float vG = wred(accs[t] * cG);
        if (lane == 0) {
            sA[r0 + t] = vA; sB[r0 + t] = vB; sC[r0 + t] = vC; sD[r0 + t] = vD;
            gam[r0 + t] = 1.f / (1.f + __expf(-(vG + bias)));
        }
    }
}

// ---------------- row-major relation (gg, cc, gc)
// Wave-private double-buffered async adjacency staging via global_load_lds.
// No __syncthreads anywhere: each wave stages its own 16 rows and syncs with
// explicit s_waitcnt vmcnt(N). 16 x 1KB loads in flight per wave = 64 KB/CU.
// LDS row stride 260 ints (1040 B): per-instr base is wave-uniform so padding
// between rows is legal, and 4m+8kp bank map is optimal for ds_read_b128.
__global__ __launch_bounds__(256, 1) void rel_row(
    const int* __restrict__ adj, int adj_ld,
    const float* __restrict__ s1, const float* __restrict__ s2,
    const unsigned short* __restrict__ hT, int Nd,
    float* __restrict__ num, float* __restrict__ lsum, int Ns, int JS)
{
    __shared__ int smem[4 * 2 * 16 * 260];     // 133120 B -> 1 block/CU
    const int wave = threadIdx.x >> 6, lane = threadIdx.x & 63;
    const int m = lane & 15, kp = lane >> 4;
    const int strip = blockIdx.x, p = blockIdx.y;
    const int jlen = Nd / JS, jbase = p * jlen;
    const int i0w = strip * 64 + wave * 16;
    const float s1v = s1[i0w + m];
    int* wbuf = smem + wave * (2 * 16 * 260);
    const int* arow = adj + (size_t)i0w * adj_ld + jbase;

    const unsigned short* hb0 = hT + (size_t)(0 * 16 + m) * Nd;
    const unsigned short* hb1 = hT + (size_t)(1 * 16 + m) * Nd;
    const unsigned short* hb2 = hT + (size_t)(2 * 16 + m) * Nd;
    const unsigned short* hb3 = hT + (size_t)(3 * 16 + m) * Nd;

    f32x4 acc0 = {0.f, 0.f, 0.f, 0.f}, acc1 = acc0, acc2 = acc0, acc3 = acc0;
    float lacc = 0.f;
    const int NCH = jlen >> 8;                 // 256-j chunks

    {   // stage chunk 0 into buf 0: 16 instrs, 1 KB each (lane*16B coalesced)
        int* dst = wbuf;
#pragma unroll
        for (int r = 0; r < 16; ++r)
            __builtin_amdgcn_global_load_lds(AS1C(arow + (size_t)r * adj_ld + lane * 4),
                                             AS3(dst + r * 260), 16, 0, 0);
    }
    for (int c = 0; c < NCH; ++c) {
        int* cur = wbuf + (c & 1) * (16 * 260);
        if (c + 1 < NCH) {
            int* dst = wbuf + ((c + 1) & 1) * (16 * 260);
            const int* src = arow + (c + 1) * 256;
#pragma unroll
            for (int r = 0; r < 16; ++r)
                __builtin_amdgcn_global_load_lds(AS1C(src + (size_t)r * adj_ld + lane * 4),
                                                 AS3(dst + r * 260), 16, 0, 0);
            // newest 16 = next chunk's stages; everything older (this chunk) drained
            asm volatile("s_waitcnt vmcnt(16)" ::: "memory");
        } else {
            asm volatile("s_waitcnt vmcnt(0)" ::: "memory");
        }
        const int jc = jbase + c * 256;
#pragma unroll
        for (int g = 0; g < 8; ++g) {
            const int jg = jc + g * 32 + kp * 8;
            float4 sa = *(const float4*)&s2[jg];
            float4 sb = *(const float4*)&s2[jg + 4];
            const int* ap = cur + m * 260 + g * 32 + kp * 8;
            int4 a0 = *(const int4*)ap;
            int4 a1 = *(const int4*)(ap + 4);
            bf16x8 b0 = *(const bf16x8*)&hb0[jg];
            bf16x8 b1 = *(const bf16x8*)&hb1[jg];
            bf16x8 b2 = *(const bf16x8*)&hb2[jg];
            bf16x8 b3 = *(const bf16x8*)&hb3[jg];
            float s2v[8] = {sa.x, sa.y, sa.z, sa.w, sb.x, sb.y, sb.z, sb.w};
            int am[8] = {a0.x, a0.y, a0.z, a0.w, a1.x, a1.y, a1.z, a1.w};
            bf16x8 af;
#pragma unroll
            for (int t = 0; t < 8; t++) {
                float e = s1v + s2v[t];
                float w = (am[t] > 0) ? __expf(leakyf(e)) : 0.f;
                lacc += w;
                af[t] = (short)f2bf(w);
            }
            acc0 = __builtin_amdgcn_mfma_f32_16x16x32_bf16(af, b0, acc0, 0, 0, 0);
            acc1 = __builtin_amdgcn_mfma_f32_16x16x32_bf16(af, b1, acc1, 0, 0, 0);
            acc2 = __builtin_amdgcn_mfma_f32_16x16x32_bf16(af, b2, acc2, 0, 0, 0);
            acc3 = __builtin_amdgcn_mfma_f32_16x16x32_bf16(af, b3, acc3, 0, 0, 0);
        }
    }
    const int orow0 = strip * 64 + wave * 16 + kp * 4;
#pragma unroll
    for (int r = 0; r < 4; r++) {
        size_t base = ((size_t)p * Ns + orow0 + r) * 64;
        num[base + m]      = acc0[r];
        num[base + 16 + m] = acc1[r];
        num[base + 32 + m] = acc2[r];
        num[base + 48 + m] = acc3[r];
    }
    lacc += __shfl_xor(lacc, 16, 64);
    lacc += __shfl_xor(lacc, 32, 64);
    if (kp == 0) lsum[(size_t)p * Ns + strip * 64 + wave * 16 + m] = lacc;
}

// ---------------- column relation (cg): adj accessed as adj[j][i]
// Coalesced column staging: each instr = 64 lanes x 4 B over 4 j-rows x 16 i
// (lane-contiguous in i). Quad stride 68 ints -> 2-way banks on read (free).
__global__ __launch_bounds__(256, 2) void rel_col(
    const int* __restrict__ adj, int adj_ld,
    const float* __restrict__ s1, const float* __restrict__ s2,
    const unsigned short* __restrict__ hT, int Nd,
    float* __restrict__ num, float* __restrict__ lsum, int Ns, int JS)
{
    __shared__ int smem[4 * 2 * 32 * 68];      // 69632 B -> 2 blocks/CU
    const int wave = threadIdx.x >> 6, lane = threadIdx.x & 63;
    const int m = lane & 15, kp = lane >> 4;
    const int strip = blockIdx.x, p = blockIdx.y;
    const int jlen = Nd / JS, jbase = p * jlen;
    const int i0w = strip * 64 + wave * 16;
    const float s1v = s1[i0w + m];
    int* wbuf = smem + wave * (2 * 32 * 68);
    const int lr = lane >> 4, li = lane & 15;  // staging: j-subrow, i-offset

    const unsigned short* hb0 = hT + (size_t)(0 * 16 + m) * Nd;
    const unsigned short* hb1 = hT + (size_t)(1 * 16 + m) * Nd;
    const unsigned short* hb2 = hT + (size_t)(2 * 16 + m) * Nd;
    const unsigned short* hb3 = hT + (size_t)(3 * 16 + m) * Nd;

    f32x4 acc0 = {0.f, 0.f, 0.f, 0.f}, acc1 = acc0, acc2 = acc0, acc3 = acc0;
    float lacc = 0.f;
    const int NCH = jlen >> 7;                 // 128-j chunks

    {   // stage chunk 0: 32 instrs, 256 B each
        int* dst = wbuf;
#pragma unroll
        for (int q = 0; q < 32; ++q)
            __builtin_amdgcn_global_load_lds(
                AS1C(adj + (size_t)(jbase + q * 4 + lr) * adj_ld + i0w + li),
                AS3(dst + q * 68), 4, 0, 0);
    }
    for (int c = 0; c < NCH; ++c) {
        int* cur = wbuf + (c & 1) * (32 * 68);
        if (c + 1 < NCH) {
            int* dst = wbuf + ((c + 1) & 1) * (32 * 68);
            const int jn = jbase + (c + 1) * 128;
#pragma unroll
            for (int q = 0; q < 32; ++q)
                __builtin_amdgcn_global_load_lds(
                    AS1C(adj + (size_t)(jn + q * 4 + lr) * adj_ld + i0w + li),
                    AS3(dst + q * 68), 4, 0, 0);
            asm volatile("s_waitcnt vmcnt(32)" ::: "memory");
        } else {
            asm volatile("s_waitcnt vmcnt(0)" ::: "memory");
        }
        const int jc = jbase + c * 128;
#pragma unroll
        for (int g = 0; g < 4; ++g) {
            const int jg = jc + g * 32 + kp * 8;
            float4 sa = *(const float4*)&s2[jg];
            float4 sb = *(const float4*)&s2[jg + 4];
            const int* ap = cur + (g * 8 + kp * 2) * 68 + m;
            int am[8];
#pragma unroll
            for (int t = 0; t < 8; t++)
                am[t] = ap[(t >> 2) * 68 + (t & 3) * 16];
            bf16x8 b0 = *(const bf16x8*)&hb0[jg];
            bf16x8 b1 = *(const bf16x8*)&hb1[jg];
            bf16x8 b2 = *(const bf16x8*)&hb2[jg];
            bf16x8 b3 = *(const bf16x8*)&hb3[jg];
            float s2v[8] = {sa.x, sa.y, sa.z, sa.w, sb.x, sb.y, sb.z, sb.w};
            bf16x8 af;
#pragma unroll
            for (int t = 0; t < 8; t++) {
                float e = s1v + s2v[t];
                float w = (am[t] > 0) ? __expf(leakyf(e)) : 0.f;
                lacc += w;
                af[t] = (short)f2bf(w);
            }
            acc0 = __builtin_amdgcn_mfma_f32_16x16x32_bf16(af, b0, acc0, 0, 0, 0);
            acc1 = __builtin_amdgcn_mfma_f32_16x16x32_bf16(af, b1, acc1, 0, 0, 0);
            acc2 = __builtin_amdgcn_mfma_f32_16x16x32_bf16(af, b2, acc2, 0, 0, 0);
            acc3 = __builtin_amdgcn_mfma_f32_16x16x32_bf16(af, b3, acc3, 0, 0, 0);
        }
    }
    const int orow0 = strip * 64 + wave * 16 + kp * 4;
#pragma unroll
    for (int r = 0; r < 4; r++) {
        size_t base = ((size_t)p * Ns + orow0 + r) * 64;
        num[base + m]      = acc0[r];
        num[base + 16 + m] = acc1[r];
        num[base + 32 + m] = acc2[r];
        num[base + 48 + m] = acc3[r];
    }
    lacc += __shfl_xor(lacc, 16, 64);
    lacc += __shfl_xor(lacc, 32, 64);
    if (kp == 0) lsum[(size_t)p * Ns + strip * 64 + wave * 16 + m] = lacc;
}

// ---------------- fused combine + epilogue: out = leaky(h + numS/lS + gam*numX/lX)
__global__ __launch_bounds__(256) void combine_final(
    const float* __restrict__ numS, const float* __restrict__ lS, int JSS,
    const float* __restrict__ numX, const float* __restrict__ lX, int JSX,
    int Ns, const float* __restrict__ h, const float* __restrict__ gam,
    float* __restrict__ out)
{
    int idx = blockIdx.x * 256 + threadIdx.x;
    int i = idx >> 6, c = idx & 63;
    float nS = 0.f, dS = 0.f, nX = 0.f, dX = 0.f;
    for (int p = 0; p < JSS; p++) {
        nS += numS[((size_t)p * Ns + i) * 64 + c];
        dS += lS[(size_t)p * Ns + i];
    }
    for (int p = 0; p < JSX; p++) {
        nX += numX[((size_t)p * Ns + i) * 64 + c];
        dX += lX[(size_t)p * Ns + i];
    }
    float v = h[idx] + nS / dS + gam[i] * (nX / dX);
    out[idx] = leakyf(v);
}

extern "C" void kernel_launch(void* const* d_in, const int* in_sizes, int n_in,
                              void* d_out, int out_size, void* d_ws, size_t ws_size,
                              hipStream_t stream)
{
    const float* gene_x = (const float*)d_in[0];
    const float* cell_x = (const float*)d_in[1];
    const float* W_g    = (const float*)d_in[2];
    const float* W_c    = (const float*)d_in[3];
    const float* a_gg   = (const float*)d_in[4];
    const float* a_gc   = (const float*)d_in[5];
    const float* a_cc   = (const float*)d_in[6];
    const float* a_cg   = (const float*)d_in[7];
    const float* Wgg    = (const float*)d_in[8];
    const float* bgg    = (const float*)d_in[9];
    const float* Wgc    = (const float*)d_in[10];
    const float* bgc    = (const float*)d_in[11];
    const int* gene_adj = (const int*)d_in[12];
    const int* cell_adj = (const int*)d_in[13];
    const int* gc_adj   = (const int*)d_in[14];

    size_t off = 0;
    char* wsb = (char*)d_ws;
    auto alloc = [&](size_t bytes) -> void* {
        void* p = wsb + off;
        off += (bytes + 255) & ~(size_t)255;
        return p;
    };
    // grids: row kernels 256 blocks (1 block/CU), col kernel 512 (2/CU)
    const int JS_GG = 2, JS_CC = 4, JS_GC = 2, JS_CG = 8;

    float* gene_h = (float*)alloc((size_t)NG * 64 * 4);
    float* cell_h = (float*)alloc((size_t)NC * 64 * 4);
    unsigned short* gene_hT = (unsigned short*)alloc((size_t)NG * 64 * 2);
    unsigned short* cell_hT = (unsigned short*)alloc((size_t)NC * 64 * 2);
    float* s1gg = (float*)alloc(NG * 4);
    float* s2gg = (float*)alloc(NG * 4);
    float* s1gc = (float*)alloc(NG * 4);
    float* s2cg = (float*)alloc(NG * 4);
    float* gamg = (float*)alloc(NG * 4);
    float* s1cc = (float*)alloc(NC * 4);
    float* s2cc = (float*)alloc(NC * 4);
    float* s2gc = (float*)alloc(NC * 4);
    float* s1cg = (float*)alloc(NC * 4);
    float* gamc = (float*)alloc(NC * 4);
    float* numGG = (float*)alloc((size_t)NG * 64 * JS_GG * 4);  // 4 MB
    float* lGG   = (float*)alloc((size_t)NG * JS_GG * 4);
    float* numGC = (float*)alloc((size_t)NG * 64 * JS_GC * 4);  // 4 MB
    float* lGC   = (float*)alloc((size_t)NG * JS_GC * 4);
    float* numCC = (float*)alloc((size_t)NC * 64 * JS_CC * 4);  // 4 MB
    float* lCC   = (float*)alloc((size_t)NC * JS_CC * 4);
    float* numCG = (float*)alloc((size_t)NC * 64 * JS_CG * 4);  // 8 MB
    float* lCG   = (float*)alloc((size_t)NC * JS_CG * 4);

    float* out_gene = (float*)d_out;
    float* out_cell = (float*)d_out + (size_t)NG * 64;

    // projections (+ per-node scalars)
    proj_kernel<<<NG / 16, 256, 0, stream>>>(gene_x, W_g, FG, NG, gene_h, gene_hT,
        a_gg, a_gg + 64, a_gc, a_cg + 64, Wgg, bgg, s1gg, s2gg, s1gc, s2cg, gamg);
    proj_kernel<<<NC / 16, 256, 0, stream>>>(cell_x, W_c, FC, NC, cell_h, cell_hT,
        a_cc, a_cc + 64, a_gc + 64, a_cg, Wgc, bgc, s1cc, s2cc, s2gc, s1cg, gamc);

    // 4 relations (gc then cg keeps gc_adj L3-warm)
    rel_row<<<dim3(NG / 64, JS_GG), 256, 0, stream>>>(gene_adj, NG, s1gg, s2gg,
        gene_hT, NG, numGG, lGG, NG, JS_GG);
    rel_row<<<dim3(NC / 64, JS_CC), 256, 0, stream>>>(cell_adj, NC, s1cc, s2cc,
        cell_hT, NC, numCC, lCC, NC, JS_CC);
    rel_row<<<dim3(NG / 64, JS_GC), 256, 0, stream>>>(gc_adj, NC, s1gc, s2gc,
        cell_hT, NC, numGC, lGC, NG, JS_GC);
    rel_col<<<dim3(NC / 64, JS_CG), 256, 0, stream>>>(gc_adj, NC, s1cg, s2cg,
        gene_hT, NG, numCG, lCG, NC, JS_CG);

    // fused combine + epilogue
    combine_final<<<NG * 64 / 256, 256, 0, stream>>>(numGG, lGG, JS_GG, numGC, lGC, JS_GC,
        NG, gene_h, gamg, out_gene);
    combine_final<<<NC * 64 / 256, 256, 0, stream>>>(numCC, lCC, JS_CC, numCG, lCG, JS_CG,
        NC, cell_h, gamc, out_cell);
}

// Round 5
// 764.982 us; speedup vs baseline: 1.0092x; 1.0092x over previous
//
#include <hip/hip_runtime.h>

#define NG 8192
#define NC 4096
#define FG 512
#define FC 256
#define ALPHA 0.2f

typedef float f32x4 __attribute__((ext_vector_type(4)));
typedef short bf16x8 __attribute__((ext_vector_type(8)));

static __device__ __forceinline__ float leakyf(float x) { return fmaxf(x, ALPHA * x); }

static __device__ __forceinline__ unsigned short f2bf(float f) {
    unsigned u = __builtin_bit_cast(unsigned, f);
    u += 0x7fffu + ((u >> 16) & 1u);          // RNE; w>=0, no NaN here
    return (unsigned short)(u >> 16);
}

static __device__ __forceinline__ float wred(float v) {
#pragma unroll
    for (int m = 1; m < 64; m <<= 1) v += __shfl_xor(v, m, 64);
    return v;
}

// ---------------- bitmask prepass: adj (int32 0/1) -> 1 bit. Pure sequential
// stream, the access pattern that measurably runs at ~6.5 TB/s on this chip.
__global__ __launch_bounds__(256) void pack_bits(
    const int* __restrict__ adj, int C, unsigned char* __restrict__ bm)
{
    const int wave = threadIdx.x >> 6, lane = threadIdx.x & 63;
    const int r = blockIdx.x * 4 + wave;
    const int* row = adj + (size_t)r * C;
    unsigned char* brow = bm + (size_t)r * (C >> 3);
    for (int j = lane * 8; j < C; j += 512) {
        int4 a0 = *(const int4*)(row + j);
        int4 a1 = *(const int4*)(row + j + 4);
        unsigned b = (unsigned)(a0.x > 0)        | ((unsigned)(a0.y > 0) << 1)
                   | ((unsigned)(a0.z > 0) << 2) | ((unsigned)(a0.w > 0) << 3)
                   | ((unsigned)(a1.x > 0) << 4) | ((unsigned)(a1.y > 0) << 5)
                   | ((unsigned)(a1.z > 0) << 6) | ((unsigned)(a1.w > 0) << 7);
        brow[j >> 3] = (unsigned char)b;
    }
}

// ---------------- projection: h = x@W  [N,K]@[K,64], + bf16 h^T, + 5 per-node scalars
__global__ __launch_bounds__(256) void proj_kernel(
    const float* __restrict__ x, const float* __restrict__ W, int K, int N,
    float* __restrict__ h, unsigned short* __restrict__ hT,
    const float* __restrict__ aA, const float* __restrict__ aB,
    const float* __restrict__ aC, const float* __restrict__ aD,
    const float* __restrict__ aG, const float* __restrict__ bG,
    float* __restrict__ sA, float* __restrict__ sB, float* __restrict__ sC,
    float* __restrict__ sD, float* __restrict__ gam)
{
    const int wave = threadIdx.x >> 6, lane = threadIdx.x & 63;
    const int r0 = blockIdx.x * 16 + wave * 4;     // 4 rows per wave
    const float* xr = x + (size_t)r0 * K;
    float acc0 = 0.f, acc1 = 0.f, acc2 = 0.f, acc3 = 0.f;
    for (int k = 0; k < K; k += 4) {
        float4 x0 = *(const float4*)(xr + k);
        float4 x1 = *(const float4*)(xr + K + k);
        float4 x2 = *(const float4*)(xr + 2 * (size_t)K + k);
        float4 x3 = *(const float4*)(xr + 3 * (size_t)K + k);
        float w0 = W[(k + 0) * 64 + lane];
        float w1 = W[(k + 1) * 64 + lane];
        float w2 = W[(k + 2) * 64 + lane];
        float w3 = W[(k + 3) * 64 + lane];
        acc0 += x0.x * w0 + x0.y * w1 + x0.z * w2 + x0.w * w3;
        acc1 += x1.x * w0 + x1.y * w1 + x1.z * w2 + x1.w * w3;
        acc2 += x2.x * w0 + x2.y * w1 + x2.z * w2 + x2.w * w3;
        acc3 += x3.x * w0 + x3.y * w1 + x3.z * w2 + x3.w * w3;
    }
    float accs[4] = {acc0, acc1, acc2, acc3};
    unsigned short hb[4];
#pragma unroll
    for (int t = 0; t < 4; t++) {
        h[(size_t)(r0 + t) * 64 + lane] = accs[t];
        hb[t] = f2bf(accs[t]);
    }
    *(ushort4*)&hT[(size_t)lane * N + r0] = make_ushort4(hb[0], hb[1], hb[2], hb[3]);

    const float cA = aA[lane], cB = aB[lane], cC = aC[lane], cD = aD[lane], cG = aG[lane];
    const float bias = bG[0];
#pragma unroll
    for (int t = 0; t < 4; t++) {
        float vA = wred(accs[t] * cA);
        float vB = wred(accs[t] * cB);
        float vC = wred(accs[t] * cC);
        float vD = wred(accs[t] * cD);
        float vG = wred(accs[t] * cG);
        if (lane == 0) {
            sA[r0 + t] = vA; sB[r0 + t] = vB; sC[r0 + t] = vC; sD[r0 + t] = vD;
            gam[r0 + t] = 1.f / (1.f + __expf(-(vG + bias)));
        }
    }
}

// ---------------- row relation (gg, cc, gc) on the bitmask
// Per chunk: 32 B of bitmask per lane (L2/L3-hot) + 32 KB hT staging (L2-hot).
// No HBM-latency stream anywhere in the wave's dependent chain.
__global__ __launch_bounds__(256, 4) void rel_row(
    const unsigned char* __restrict__ bm, int bm_ld,
    const float* __restrict__ s1, const float* __restrict__ s2,
    const unsigned short* __restrict__ hT, int Nd,
    float* __restrict__ num, float* __restrict__ lsum, int Ns, int JS)
{
    __shared__ unsigned short hbuf[64 * 264];      // 33792 B -> 4 blocks/CU
    const int wave = threadIdx.x >> 6, lane = threadIdx.x & 63;
    const int m = lane & 15, kp = lane >> 4;
    const int strip = blockIdx.x, p = blockIdx.y;
    const int jlen = Nd / JS, jbase = p * jlen;
    const int i_row = strip * 64 + wave * 16 + m;
    const float s1v = s1[i_row];
    const unsigned char* bmrow = bm + (size_t)i_row * bm_ld;
    f32x4 acc0 = {0.f, 0.f, 0.f, 0.f}, acc1 = acc0, acc2 = acc0, acc3 = acc0;
    float lacc = 0.f;

    for (int jc = jbase; jc < jbase + jlen; jc += 256) {
        // bitmask for this chunk: bytes [jc/8, jc/8+32); byte kp of word g
        uint4 q0 = *(const uint4*)(bmrow + (jc >> 3));
        uint4 q1 = *(const uint4*)(bmrow + (jc >> 3) + 16);
        // stage hT chunk [64 dims][256 j] (L2-hot, 8 indep loads/thread)
        for (int idx = threadIdx.x; idx < 2048; idx += 256) {
            int c = idx >> 5, off = (idx & 31) * 8;
            *(int4*)&hbuf[c * 264 + off] = *(const int4*)&hT[(size_t)c * Nd + jc + off];
        }
        __syncthreads();
        unsigned words[8] = {q0.x, q0.y, q0.z, q0.w, q1.x, q1.y, q1.z, q1.w};
#pragma unroll
        for (int g = 0; g < 8; ++g) {
            const int jg = jc + g * 32 + kp * 8;
            float4 sa = *(const float4*)&s2[jg];
            float4 sb = *(const float4*)&s2[jg + 4];
            unsigned byte = (words[g] >> (kp * 8)) & 0xffu;
            const int lb = g * 32 + kp * 8;
            bf16x8 b0 = *(const bf16x8*)&hbuf[(0 * 16 + m) * 264 + lb];
            bf16x8 b1 = *(const bf16x8*)&hbuf[(1 * 16 + m) * 264 + lb];
            bf16x8 b2 = *(const bf16x8*)&hbuf[(2 * 16 + m) * 264 + lb];
            bf16x8 b3 = *(const bf16x8*)&hbuf[(3 * 16 + m) * 264 + lb];
            float s2v[8] = {sa.x, sa.y, sa.z, sa.w, sb.x, sb.y, sb.z, sb.w};
            bf16x8 af;
#pragma unroll
            for (int t = 0; t < 8; t++) {
                float e = s1v + s2v[t];
                float w = ((byte >> t) & 1u) ? __expf(leakyf(e)) : 0.f;
                lacc += w;
                af[t] = (short)f2bf(w);
            }
            acc0 = __builtin_amdgcn_mfma_f32_16x16x32_bf16(af, b0, acc0, 0, 0, 0);
            acc1 = __builtin_amdgcn_mfma_f32_16x16x32_bf16(af, b1, acc1, 0, 0, 0);
            acc2 = __builtin_amdgcn_mfma_f32_16x16x32_bf16(af, b2, acc2, 0, 0, 0);
            acc3 = __builtin_amdgcn_mfma_f32_16x16x32_bf16(af, b3, acc3, 0, 0, 0);
        }
        __syncthreads();
    }
    // C/D layout: col = lane&15 (+16q), row = (lane>>4)*4 + r
    const int orow0 = strip * 64 + wave * 16 + kp * 4;
#pragma unroll
    for (int r = 0; r < 4; r++) {
        size_t base = ((size_t)p * Ns + orow0 + r) * 64;
        num[base + m]      = acc0[r];
        num[base + 16 + m] = acc1[r];
        num[base + 32 + m] = acc2[r];
        num[base + 48 + m] = acc3[r];
    }
    lacc += __shfl_xor(lacc, 16, 64);
    lacc += __shfl_xor(lacc, 32, 64);
    if (kp == 0) lsum[(size_t)p * Ns + strip * 64 + wave * 16 + m] = lacc;
}

// ---------------- column relation (cg): bit[j][i] from row-major gc bitmask.
// Stage the 1 KB bitmask column-slice + 16 KB hT per 128-j chunk into LDS.
__global__ __launch_bounds__(256, 4) void rel_col(
    const unsigned char* __restrict__ bm, int bm_ld,    // bmGC: row j (gene), byte cols = cells/8
    const float* __restrict__ s1, const float* __restrict__ s2,
    const unsigned short* __restrict__ hT, int Nd,      // Nd = NG
    float* __restrict__ num, float* __restrict__ lsum, int Ns, int JS)
{
    __shared__ unsigned short hbuf[64 * 136];           // 17408 B
    __shared__ unsigned char bmb[128 * 8];              // 1 KB
    const int wave = threadIdx.x >> 6, lane = threadIdx.x & 63;
    const int m = lane & 15, kp = lane >> 4;
    const int strip = blockIdx.x, p = blockIdx.y;
    const int jlen = Nd / JS, jbase = p * jlen;
    const int i0 = strip * 64;
    const float s1v = s1[i0 + wave * 16 + m];
    f32x4 acc0 = {0.f, 0.f, 0.f, 0.f}, acc1 = acc0, acc2 = acc0, acc3 = acc0;
    float lacc = 0.f;
    const int bidx = wave * 2 + (m >> 3);               // byte within 8-byte row
    const int bbit = m & 7;

    for (int jc = jbase; jc < jbase + jlen; jc += 128) {
        // stage bitmask column slice: 128 j-rows x 8 bytes (i0..i0+63 bits)
        if (threadIdx.x < 128)
            *(unsigned long long*)&bmb[threadIdx.x * 8] =
                *(const unsigned long long*)&bm[(size_t)(jc + threadIdx.x) * bm_ld + (i0 >> 3)];
        // stage hT chunk [64 dims][128 j]
        for (int idx = threadIdx.x; idx < 1024; idx += 256) {
            int c = idx >> 4, off = (idx & 15) * 8;
            *(int4*)&hbuf[c * 136 + off] = *(const int4*)&hT[(size_t)c * Nd + jc + off];
        }
        __syncthreads();
#pragma unroll
        for (int g = 0; g < 4; ++g) {
            const int jg = jc + g * 32 + kp * 8;
            float4 sa = *(const float4*)&s2[jg];
            float4 sb = *(const float4*)&s2[jg + 4];
            const int jl = g * 32 + kp * 8;
            const int lb = jl;
            bf16x8 b0 = *(const bf16x8*)&hbuf[(0 * 16 + m) * 136 + lb];
            bf16x8 b1 = *(const bf16x8*)&hbuf[(1 * 16 + m) * 136 + lb];
            bf16x8 b2 = *(const bf16x8*)&hbuf[(2 * 16 + m) * 136 + lb];
            bf16x8 b3 = *(const bf16x8*)&hbuf[(3 * 16 + m) * 136 + lb];
            float s2v[8] = {sa.x, sa.y, sa.z, sa.w, sb.x, sb.y, sb.z, sb.w};
            bf16x8 af;
#pragma unroll
            for (int t = 0; t < 8; t++) {
                unsigned byte = bmb[(jl + t) * 8 + bidx];
                float e = s1v + s2v[t];
                float w = ((byte >> bbit) & 1u) ? __expf(leakyf(e)) : 0.f;
                lacc += w;
                af[t] = (short)f2bf(w);
            }
            acc0 = __builtin_amdgcn_mfma_f32_16x16x32_bf16(af, b0, acc0, 0, 0, 0);
            acc1 = __builtin_amdgcn_mfma_f32_16x16x32_bf16(af, b1, acc1, 0, 0, 0);
            acc2 = __builtin_amdgcn_mfma_f32_16x16x32_bf16(af, b2, acc2, 0, 0, 0);
            acc3 = __builtin_amdgcn_mfma_f32_16x16x32_bf16(af, b3, acc3, 0, 0, 0);
        }
        __syncthreads();
    }
    const int orow0 = strip * 64 + wave * 16 + kp * 4;
#pragma unroll
    for (int r = 0; r < 4; r++) {
        size_t base = ((size_t)p * Ns + orow0 + r) * 64;
        num[base + m]      = acc0[r];
        num[base + 16 + m] = acc1[r];
        num[base + 32 + m] = acc2[r];
        num[base + 48 + m] = acc3[r];
    }
    lacc += __shfl_xor(lacc, 16, 64);
    lacc += __shfl_xor(lacc, 32, 64);
    if (kp == 0) lsum[(size_t)p * Ns + strip * 64 + wave * 16 + m] = lacc;
}

// ---------------- fused combine + epilogue: out = leaky(h + numS/lS + gam*numX/lX)
__global__ __launch_bounds__(256) void combine_final(
    const float* __restrict__ numS, const float* __restrict__ lS, int JSS,
    const float* __restrict__ numX, const float* __restrict__ lX, int JSX,
    int Ns, const float* __restrict__ h, const float* __restrict__ gam,
    float* __restrict__ out)
{
    int idx = blockIdx.x * 256 + threadIdx.x;
    int i = idx >> 6, c = idx & 63;
    float nS = 0.f, dS = 0.f, nX = 0.f, dX = 0.f;
    for (int p = 0; p < JSS; p++) {
        nS += numS[((size_t)p * Ns + i) * 64 + c];
        dS += lS[(size_t)p * Ns + i];
    }
    for (int p = 0; p < JSX; p++) {
        nX += numX[((size_t)p * Ns + i) * 64 + c];
        dX += lX[(size_t)p * Ns + i];
    }
    float v = h[idx] + nS / dS + gam[i] * (nX / dX);
    out[idx] = leakyf(v);
}

extern "C" void kernel_launch(void* const* d_in, const int* in_sizes, int n_in,
                              void* d_out, int out_size, void* d_ws, size_t ws_size,
                              hipStream_t stream)
{
    const float* gene_x = (const float*)d_in[0];
    const float* cell_x = (const float*)d_in[1];
    const float* W_g    = (const float*)d_in[2];
    const float* W_c    = (const float*)d_in[3];
    const float* a_gg   = (const float*)d_in[4];
    const float* a_gc   = (const float*)d_in[5];
    const float* a_cc   = (const float*)d_in[6];
    const float* a_cg   = (const float*)d_in[7];
    const float* Wgg    = (const float*)d_in[8];
    const float* bgg    = (const float*)d_in[9];
    const float* Wgc    = (const float*)d_in[10];
    const float* bgc    = (const float*)d_in[11];
    const int* gene_adj = (const int*)d_in[12];
    const int* cell_adj = (const int*)d_in[13];
    const int* gc_adj   = (const int*)d_in[14];

    size_t off = 0;
    char* wsb = (char*)d_ws;
    auto alloc = [&](size_t bytes) -> void* {
        void* p = wsb + off;
        off += (bytes + 255) & ~(size_t)255;
        return p;
    };
    const int JS_GG = 4, JS_CC = 8, JS_GC = 4, JS_CG = 8;   // all grids = 512 blocks

    float* gene_h = (float*)alloc((size_t)NG * 64 * 4);
    float* cell_h = (float*)alloc((size_t)NC * 64 * 4);
    unsigned short* gene_hT = (unsigned short*)alloc((size_t)NG * 64 * 2);
    unsigned short* cell_hT = (unsigned short*)alloc((size_t)NC * 64 * 2);
    unsigned char* bmGG = (unsigned char*)alloc((size_t)NG * (NG / 8));   // 8 MB
    unsigned char* bmCC = (unsigned char*)alloc((size_t)NC * (NC / 8));   // 2 MB
    unsigned char* bmGC = (unsigned char*)alloc((size_t)NG * (NC / 8));   // 4 MB
    float* s1gg = (float*)alloc(NG * 4);
    float* s2gg = (float*)alloc(NG * 4);
    float* s1gc = (float*)alloc(NG * 4);
    float* s2cg = (float*)alloc(NG * 4);
    float* gamg = (float*)alloc(NG * 4);
    float* s1cc = (float*)alloc(NC * 4);
    float* s2cc = (float*)alloc(NC * 4);
    float* s2gc = (float*)alloc(NC * 4);
    float* s1cg = (float*)alloc(NC * 4);
    float* gamc = (float*)alloc(NC * 4);
    float* numGG = (float*)alloc((size_t)NG * 64 * JS_GG * 4);  // 8 MB
    float* lGG   = (float*)alloc((size_t)NG * JS_GG * 4);
    float* numGC = (float*)alloc((size_t)NG * 64 * JS_GC * 4);  // 8 MB
    float* lGC   = (float*)alloc((size_t)NG * JS_GC * 4);
    float* numCC = (float*)alloc((size_t)NC * 64 * JS_CC * 4);  // 8 MB
    float* lCC   = (float*)alloc((size_t)NC * JS_CC * 4);
    float* numCG = (float*)alloc((size_t)NC * 64 * JS_CG * 4);  // 8 MB
    float* lCG   = (float*)alloc((size_t)NC * JS_CG * 4);

    float* out_gene = (float*)d_out;
    float* out_cell = (float*)d_out + (size_t)NG * 64;

    // bitmask prepasses: the ONLY kernels that touch the 448 MB of adjacency,
    // with a purely sequential pattern that streams at HBM rate.
    pack_bits<<<NG / 4, 256, 0, stream>>>(gene_adj, NG, bmGG);
    pack_bits<<<NC / 4, 256, 0, stream>>>(cell_adj, NC, bmCC);
    pack_bits<<<NG / 4, 256, 0, stream>>>(gc_adj, NC, bmGC);

    // projections (+ per-node scalars) — overlap-friendly, ordered after packs
    proj_kernel<<<NG / 16, 256, 0, stream>>>(gene_x, W_g, FG, NG, gene_h, gene_hT,
        a_gg, a_gg + 64, a_gc, a_cg + 64, Wgg, bgg, s1gg, s2gg, s1gc, s2cg, gamg);
    proj_kernel<<<NC / 16, 256, 0, stream>>>(cell_x, W_c, FC, NC, cell_h, cell_hT,
        a_cc, a_cc + 64, a_gc + 64, a_cg, Wgc, bgc, s1cc, s2cc, s2gc, s1cg, gamc);

    // 4 relations on bitmasks (all L2/L3-resident)
    rel_row<<<dim3(NG / 64, JS_GG), 256, 0, stream>>>(bmGG, NG / 8, s1gg, s2gg,
        gene_hT, NG, numGG, lGG, NG, JS_GG);
    rel_row<<<dim3(NC / 64, JS_CC), 256, 0, stream>>>(bmCC, NC / 8, s1cc, s2cc,
        cell_hT, NC, numCC, lCC, NC, JS_CC);
    rel_row<<<dim3(NG / 64, JS_GC), 256, 0, stream>>>(bmGC, NC / 8, s1gc, s2gc,
        cell_hT, NC, numGC, lGC, NG, JS_GC);
    rel_col<<<dim3(NC / 64, JS_CG), 256, 0, stream>>>(bmGC, NC / 8, s1cg, s2cg,
        gene_hT, NG, numCG, lCG, NC, JS_CG);

    // fused combine + epilogue
    combine_final<<<NG * 64 / 256, 256, 0, stream>>>(numGG, lGG, JS_GG, numGC, lGC, JS_GC,
        NG, gene_h, gamg, out_gene);
    combine_final<<<NC * 64 / 256, 256, 0, stream>>>(numCC, lCC, JS_CC, numCG, lCG, JS_CG,
        NC, cell_h, gamc, out_cell);
}

// Round 6
// 692.449 us; speedup vs baseline: 1.1149x; 1.1047x over previous
//
#include <hip/hip_runtime.h>

#define NG 8192
#define NC 4096
#define FG 512
#define FC 256
#define ALPHA 0.2f

typedef float f32x4 __attribute__((ext_vector_type(4)));
typedef short bf16x8 __attribute__((ext_vector_type(8)));

static __device__ __forceinline__ float leakyf(float x) { return fmaxf(x, ALPHA * x); }

static __device__ __forceinline__ unsigned short f2bf(float f) {
    unsigned u = __builtin_bit_cast(unsigned, f);
    u += 0x7fffu + ((u >> 16) & 1u);          // RNE; w>=0, no NaN here
    return (unsigned short)(u >> 16);
}

static __device__ __forceinline__ float wred(float v) {
#pragma unroll
    for (int m = 1; m < 64; m <<= 1) v += __shfl_xor(v, m, 64);
    return v;
}

// ---------------- fused bitmask prepass: all 3 adjacencies -> 1-bit masks.
// One launch; rows of (gene_adj | cell_adj | gc_adj) flat-indexed.
__global__ __launch_bounds__(256) void pack_all(
    const int* __restrict__ gene_adj, const int* __restrict__ cell_adj,
    const int* __restrict__ gc_adj,
    unsigned char* __restrict__ bmGG, unsigned char* __restrict__ bmCC,
    unsigned char* __restrict__ bmGC)
{
    const int wave = threadIdx.x >> 6, lane = threadIdx.x & 63;
    const int r = blockIdx.x * 4 + wave;
    const int* row; unsigned char* brow; int C;
    if (r < NG)           { row = gene_adj + (size_t)r * NG;              brow = bmGG + (size_t)r * (NG >> 3);              C = NG; }
    else if (r < NG + NC) { int rr = r - NG;      row = cell_adj + (size_t)rr * NC; brow = bmCC + (size_t)rr * (NC >> 3); C = NC; }
    else                  { int rr = r - NG - NC; row = gc_adj   + (size_t)rr * NC; brow = bmGC + (size_t)rr * (NC >> 3); C = NC; }
    for (int j = lane * 8; j < C; j += 512) {
        int4 a0 = *(const int4*)(row + j);
        int4 a1 = *(const int4*)(row + j + 4);
        unsigned b = (unsigned)(a0.x > 0)        | ((unsigned)(a0.y > 0) << 1)
                   | ((unsigned)(a0.z > 0) << 2) | ((unsigned)(a0.w > 0) << 3)
                   | ((unsigned)(a1.x > 0) << 4) | ((unsigned)(a1.y > 0) << 5)
                   | ((unsigned)(a1.z > 0) << 6) | ((unsigned)(a1.w > 0) << 7);
        brow[j >> 3] = (unsigned char)b;
    }
}

// ---------------- projection: h = x@W  [N,K]@[K,64], + bf16 h^T, + 5 per-node scalars
__global__ __launch_bounds__(256) void proj_kernel(
    const float* __restrict__ x, const float* __restrict__ W, int K, int N,
    float* __restrict__ h, unsigned short* __restrict__ hT,
    const float* __restrict__ aA, const float* __restrict__ aB,
    const float* __restrict__ aC, const float* __restrict__ aD,
    const float* __restrict__ aG, const float* __restrict__ bG,
    float* __restrict__ sA, float* __restrict__ sB, float* __restrict__ sC,
    float* __restrict__ sD, float* __restrict__ gam)
{
    const int wave = threadIdx.x >> 6, lane = threadIdx.x & 63;
    const int r0 = blockIdx.x * 16 + wave * 4;     // 4 rows per wave
    const float* xr = x + (size_t)r0 * K;
    float acc0 = 0.f, acc1 = 0.f, acc2 = 0.f, acc3 = 0.f;
    for (int k = 0; k < K; k += 4) {
        float4 x0 = *(const float4*)(xr + k);
        float4 x1 = *(const float4*)(xr + K + k);
        float4 x2 = *(const float4*)(xr + 2 * (size_t)K + k);
        float4 x3 = *(const float4*)(xr + 3 * (size_t)K + k);
        float w0 = W[(k + 0) * 64 + lane];
        float w1 = W[(k + 1) * 64 + lane];
        float w2 = W[(k + 2) * 64 + lane];
        float w3 = W[(k + 3) * 64 + lane];
        acc0 += x0.x * w0 + x0.y * w1 + x0.z * w2 + x0.w * w3;
        acc1 += x1.x * w0 + x1.y * w1 + x1.z * w2 + x1.w * w3;
        acc2 += x2.x * w0 + x2.y * w1 + x2.z * w2 + x2.w * w3;
        acc3 += x3.x * w0 + x3.y * w1 + x3.z * w2 + x3.w * w3;
    }
    float accs[4] = {acc0, acc1, acc2, acc3};
    unsigned short hb[4];
#pragma unroll
    for (int t = 0; t < 4; t++) {
        h[(size_t)(r0 + t) * 64 + lane] = accs[t];
        hb[t] = f2bf(accs[t]);
    }
    *(ushort4*)&hT[(size_t)lane * N + r0] = make_ushort4(hb[0], hb[1], hb[2], hb[3]);

    const float cA = aA[lane], cB = aB[lane], cC = aC[lane], cD = aD[lane], cG = aG[lane];
    const float bias = bG[0];
#pragma unroll
    for (int t = 0; t < 4; t++) {
        float vA = wred(accs[t] * cA);
        float vB = wred(accs[t] * cB);
        float vC = wred(accs[t] * cC);
        float vD = wred(accs[t] * cD);
        float vG = wred(accs[t] * cG);
        if (lane == 0) {
            sA[r0 + t] = vA; sB[r0 + t] = vB; sC[r0 + t] = vC; sD[r0 + t] = vD;
            gam[r0 + t] = 1.f / (1.f + __expf(-(vG + bias)));
        }
    }
}

// ---------------- row relation body (bitmask)
static __device__ __forceinline__ void rel_row_body(
    unsigned short* hbuf,                      // [64*264] LDS
    const unsigned char* __restrict__ bm, int bm_ld,
    const float* __restrict__ s1, const float* __restrict__ s2,
    const unsigned short* __restrict__ hT, int Nd,
    float* __restrict__ num, float* __restrict__ lsum, int Ns, int JS,
    int strip, int p)
{
    const int wave = threadIdx.x >> 6, lane = threadIdx.x & 63;
    const int m = lane & 15, kp = lane >> 4;
    const int jlen = Nd / JS, jbase = p * jlen;
    const int i_row = strip * 64 + wave * 16 + m;
    const float s1v = s1[i_row];
    const unsigned char* bmrow = bm + (size_t)i_row * bm_ld;
    f32x4 acc0 = {0.f, 0.f, 0.f, 0.f}, acc1 = acc0, acc2 = acc0, acc3 = acc0;
    float lacc = 0.f;

    for (int jc = jbase; jc < jbase + jlen; jc += 256) {
        uint4 q0 = *(const uint4*)(bmrow + (jc >> 3));
        uint4 q1 = *(const uint4*)(bmrow + (jc >> 3) + 16);
        for (int idx = threadIdx.x; idx < 2048; idx += 256) {
            int c = idx >> 5, off = (idx & 31) * 8;
            *(int4*)&hbuf[c * 264 + off] = *(const int4*)&hT[(size_t)c * Nd + jc + off];
        }
        __syncthreads();
        unsigned words[8] = {q0.x, q0.y, q0.z, q0.w, q1.x, q1.y, q1.z, q1.w};
#pragma unroll
        for (int g = 0; g < 8; ++g) {
            const int jg = jc + g * 32 + kp * 8;
            float4 sa = *(const float4*)&s2[jg];
            float4 sb = *(const float4*)&s2[jg + 4];
            unsigned byte = (words[g] >> (kp * 8)) & 0xffu;
            const int lb = g * 32 + kp * 8;
            bf16x8 b0 = *(const bf16x8*)&hbuf[(0 * 16 + m) * 264 + lb];
            bf16x8 b1 = *(const bf16x8*)&hbuf[(1 * 16 + m) * 264 + lb];
            bf16x8 b2 = *(const bf16x8*)&hbuf[(2 * 16 + m) * 264 + lb];
            bf16x8 b3 = *(const bf16x8*)&hbuf[(3 * 16 + m) * 264 + lb];
            float s2v[8] = {sa.x, sa.y, sa.z, sa.w, sb.x, sb.y, sb.z, sb.w};
            bf16x8 af;
#pragma unroll
            for (int t = 0; t < 8; t++) {
                float e = s1v + s2v[t];
                float w = ((byte >> t) & 1u) ? __expf(leakyf(e)) : 0.f;
                lacc += w;
                af[t] = (short)f2bf(w);
            }
            acc0 = __builtin_amdgcn_mfma_f32_16x16x32_bf16(af, b0, acc0, 0, 0, 0);
            acc1 = __builtin_amdgcn_mfma_f32_16x16x32_bf16(af, b1, acc1, 0, 0, 0);
            acc2 = __builtin_amdgcn_mfma_f32_16x16x32_bf16(af, b2, acc2, 0, 0, 0);
            acc3 = __builtin_amdgcn_mfma_f32_16x16x32_bf16(af, b3, acc3, 0, 0, 0);
        }
        __syncthreads();
    }
    const int orow0 = strip * 64 + wave * 16 + kp * 4;
#pragma unroll
    for (int r = 0; r < 4; r++) {
        size_t base = ((size_t)p * Ns + orow0 + r) * 64;
        num[base + m]      = acc0[r];
        num[base + 16 + m] = acc1[r];
        num[base + 32 + m] = acc2[r];
        num[base + 48 + m] = acc3[r];
    }
    lacc += __shfl_xor(lacc, 16, 64);
    lacc += __shfl_xor(lacc, 32, 64);
    if (kp == 0) lsum[(size_t)p * Ns + strip * 64 + wave * 16 + m] = lacc;
}

// ---------------- column relation body (cg): bit[j][i] from row-major gc bitmask
static __device__ __forceinline__ void rel_col_body(
    unsigned short* hbuf,                      // [64*136] LDS
    unsigned char* bmb,                        // [128*8] LDS
    const unsigned char* __restrict__ bm, int bm_ld,
    const float* __restrict__ s1, const float* __restrict__ s2,
    const unsigned short* __restrict__ hT, int Nd,
    float* __restrict__ num, float* __restrict__ lsum, int Ns, int JS,
    int strip, int p)
{
    const int wave = threadIdx.x >> 6, lane = threadIdx.x & 63;
    const int m = lane & 15, kp = lane >> 4;
    const int jlen = Nd / JS, jbase = p * jlen;
    const int i0 = strip * 64;
    const float s1v = s1[i0 + wave * 16 + m];
    f32x4 acc0 = {0.f, 0.f, 0.f, 0.f}, acc1 = acc0, acc2 = acc0, acc3 = acc0;
    float lacc = 0.f;
    const int bidx = wave * 2 + (m >> 3);
    const int bbit = m & 7;

    for (int jc = jbase; jc < jbase + jlen; jc += 128) {
        if (threadIdx.x < 128)
            *(unsigned long long*)&bmb[threadIdx.x * 8] =
                *(const unsigned long long*)&bm[(size_t)(jc + threadIdx.x) * bm_ld + (i0 >> 3)];
        for (int idx = threadIdx.x; idx < 1024; idx += 256) {
            int c = idx >> 4, off = (idx & 15) * 8;
            *(int4*)&hbuf[c * 136 + off] = *(const int4*)&hT[(size_t)c * Nd + jc + off];
        }
        __syncthreads();
#pragma unroll
        for (int g = 0; g < 4; ++g) {
            const int jg = jc + g * 32 + kp * 8;
            float4 sa = *(const float4*)&s2[jg];
            float4 sb = *(const float4*)&s2[jg + 4];
            const int jl = g * 32 + kp * 8;
            bf16x8 b0 = *(const bf16x8*)&hbuf[(0 * 16 + m) * 136 + jl];
            bf16x8 b1 = *(const bf16x8*)&hbuf[(1 * 16 + m) * 136 + jl];
            bf16x8 b2 = *(const bf16x8*)&hbuf[(2 * 16 + m) * 136 + jl];
            bf16x8 b3 = *(const bf16x8*)&hbuf[(3 * 16 + m) * 136 + jl];
            float s2v[8] = {sa.x, sa.y, sa.z, sa.w, sb.x, sb.y, sb.z, sb.w};
            bf16x8 af;
#pragma unroll
            for (int t = 0; t < 8; t++) {
                unsigned byte = bmb[(jl + t) * 8 + bidx];
                float e = s1v + s2v[t];
                float w = ((byte >> bbit) & 1u) ? __expf(leakyf(e)) : 0.f;
                lacc += w;
                af[t] = (short)f2bf(w);
            }
            acc0 = __builtin_amdgcn_mfma_f32_16x16x32_bf16(af, b0, acc0, 0, 0, 0);
            acc1 = __builtin_amdgcn_mfma_f32_16x16x32_bf16(af, b1, acc1, 0, 0, 0);
            acc2 = __builtin_amdgcn_mfma_f32_16x16x32_bf16(af, b2, acc2, 0, 0, 0);
            acc3 = __builtin_amdgcn_mfma_f32_16x16x32_bf16(af, b3, acc3, 0, 0, 0);
        }
        __syncthreads();
    }
    const int orow0 = strip * 64 + wave * 16 + kp * 4;
#pragma unroll
    for (int r = 0; r < 4; r++) {
        size_t base = ((size_t)p * Ns + orow0 + r) * 64;
        num[base + m]      = acc0[r];
        num[base + 16 + m] = acc1[r];
        num[base + 32 + m] = acc2[r];
        num[base + 48 + m] = acc3[r];
    }
    lacc += __shfl_xor(lacc, 16, 64);
    lacc += __shfl_xor(lacc, 32, 64);
    if (kp == 0) lsum[(size_t)p * Ns + strip * 64 + wave * 16 + m] = lacc;
}

// ---------------- ALL four relations in ONE dispatch (diagnostic + fewer launches)
// blocks: [0,512) gg | [512,1024) cc | [1024,1536) gc | [1536,2048) cg
__global__ __launch_bounds__(256, 4) void rel_fused(
    const unsigned char* __restrict__ bmGG, const unsigned char* __restrict__ bmCC,
    const unsigned char* __restrict__ bmGC,
    const float* __restrict__ s1gg, const float* __restrict__ s2gg,
    const float* __restrict__ s1cc, const float* __restrict__ s2cc,
    const float* __restrict__ s1gc, const float* __restrict__ s2gc,
    const float* __restrict__ s1cg, const float* __restrict__ s2cg,
    const unsigned short* __restrict__ gene_hT, const unsigned short* __restrict__ cell_hT,
    float* __restrict__ numGG, float* __restrict__ lGG,
    float* __restrict__ numCC, float* __restrict__ lCC,
    float* __restrict__ numGC, float* __restrict__ lGC,
    float* __restrict__ numCG, float* __restrict__ lCG)
{
    __shared__ __align__(16) char smem[64 * 264 * 2];   // 33792 B (row needs all; col overlays)
    const int b = blockIdx.x, rel = b >> 9, w = b & 511;
    if (rel == 0) {
        rel_row_body((unsigned short*)smem, bmGG, NG / 8, s1gg, s2gg, gene_hT, NG,
                     numGG, lGG, NG, 4, w >> 2, w & 3);
    } else if (rel == 1) {
        rel_row_body((unsigned short*)smem, bmCC, NC / 8, s1cc, s2cc, cell_hT, NC,
                     numCC, lCC, NC, 8, w >> 3, w & 7);
    } else if (rel == 2) {
        rel_row_body((unsigned short*)smem, bmGC, NC / 8, s1gc, s2gc, cell_hT, NC,
                     numGC, lGC, NG, 4, w >> 2, w & 3);
    } else {
        rel_col_body((unsigned short*)smem, (unsigned char*)(smem + 64 * 136 * 2),
                     bmGC, NC / 8, s1cg, s2cg, gene_hT, NG,
                     numCG, lCG, NC, 8, w >> 3, w & 7);
    }
}

// ---------------- fused combine + epilogue: out = leaky(h + numS/lS + gam*numX/lX)
__global__ __launch_bounds__(256) void combine_final(
    const float* __restrict__ numS, const float* __restrict__ lS, int JSS,
    const float* __restrict__ numX, const float* __restrict__ lX, int JSX,
    int Ns, const float* __restrict__ h, const float* __restrict__ gam,
    float* __restrict__ out)
{
    int idx = blockIdx.x * 256 + threadIdx.x;
    int i = idx >> 6, c = idx & 63;
    float nS = 0.f, dS = 0.f, nX = 0.f, dX = 0.f;
    for (int p = 0; p < JSS; p++) {
        nS += numS[((size_t)p * Ns + i) * 64 + c];
        dS += lS[(size_t)p * Ns + i];
    }
    for (int p = 0; p < JSX; p++) {
        nX += numX[((size_t)p * Ns + i) * 64 + c];
        dX += lX[(size_t)p * Ns + i];
    }
    float v = h[idx] + nS / dS + gam[i] * (nX / dX);
    out[idx] = leakyf(v);
}

extern "C" void kernel_launch(void* const* d_in, const int* in_sizes, int n_in,
                              void* d_out, int out_size, void* d_ws, size_t ws_size,
                              hipStream_t stream)
{
    const float* gene_x = (const float*)d_in[0];
    const float* cell_x = (const float*)d_in[1];
    const float* W_g    = (const float*)d_in[2];
    const float* W_c    = (const float*)d_in[3];
    const float* a_gg   = (const float*)d_in[4];
    const float* a_gc   = (const float*)d_in[5];
    const float* a_cc   = (const float*)d_in[6];
    const float* a_cg   = (const float*)d_in[7];
    const float* Wgg    = (const float*)d_in[8];
    const float* bgg    = (const float*)d_in[9];
    const float* Wgc    = (const float*)d_in[10];
    const float* bgc    = (const float*)d_in[11];
    const int* gene_adj = (const int*)d_in[12];
    const int* cell_adj = (const int*)d_in[13];
    const int* gc_adj   = (const int*)d_in[14];

    size_t off = 0;
    char* wsb = (char*)d_ws;
    auto alloc = [&](size_t bytes) -> void* {
        void* p = wsb + off;
        off += (bytes + 255) & ~(size_t)255;
        return p;
    };
    const int JS_GG = 4, JS_CC = 8, JS_GC = 4, JS_CG = 8;   // 512 blocks per relation

    float* gene_h = (float*)alloc((size_t)NG * 64 * 4);
    float* cell_h = (float*)alloc((size_t)NC * 64 * 4);
    unsigned short* gene_hT = (unsigned short*)alloc((size_t)NG * 64 * 2);
    unsigned short* cell_hT = (unsigned short*)alloc((size_t)NC * 64 * 2);
    unsigned char* bmGG = (unsigned char*)alloc((size_t)NG * (NG / 8));   // 8 MB
    unsigned char* bmCC = (unsigned char*)alloc((size_t)NC * (NC / 8));   // 2 MB
    unsigned char* bmGC = (unsigned char*)alloc((size_t)NG * (NC / 8));   // 4 MB
    float* s1gg = (float*)alloc(NG * 4);
    float* s2gg = (float*)alloc(NG * 4);
    float* s1gc = (float*)alloc(NG * 4);
    float* s2cg = (float*)alloc(NG * 4);
    float* gamg = (float*)alloc(NG * 4);
    float* s1cc = (float*)alloc(NC * 4);
    float* s2cc = (float*)alloc(NC * 4);
    float* s2gc = (float*)alloc(NC * 4);
    float* s1cg = (float*)alloc(NC * 4);
    float* gamc = (float*)alloc(NC * 4);
    float* numGG = (float*)alloc((size_t)NG * 64 * JS_GG * 4);  // 8 MB
    float* lGG   = (float*)alloc((size_t)NG * JS_GG * 4);
    float* numGC = (float*)alloc((size_t)NG * 64 * JS_GC * 4);  // 8 MB
    float* lGC   = (float*)alloc((size_t)NG * JS_GC * 4);
    float* numCC = (float*)alloc((size_t)NC * 64 * JS_CC * 4);  // 8 MB
    float* lCC   = (float*)alloc((size_t)NC * JS_CC * 4);
    float* numCG = (float*)alloc((size_t)NC * 64 * JS_CG * 4);  // 8 MB
    float* lCG   = (float*)alloc((size_t)NC * JS_CG * 4);

    float* out_gene = (float*)d_out;
    float* out_cell = (float*)d_out + (size_t)NG * 64;

    // 1 launch: all three bitmask packs (only kernels touching the 448 MB)
    pack_all<<<(NG + NC + NG) / 4, 256, 0, stream>>>(gene_adj, cell_adj, gc_adj,
        bmGG, bmCC, bmGC);

    // projections (+ per-node scalars)
    proj_kernel<<<NG / 16, 256, 0, stream>>>(gene_x, W_g, FG, NG, gene_h, gene_hT,
        a_gg, a_gg + 64, a_gc, a_cg + 64, Wgg, bgg, s1gg, s2gg, s1gc, s2cg, gamg);
    proj_kernel<<<NC / 16, 256, 0, stream>>>(cell_x, W_c, FC, NC, cell_h, cell_hT,
        a_cc, a_cc + 64, a_gc + 64, a_cg, Wgc, bgc, s1cc, s2cc, s2gc, s1cg, gamc);

    // 1 launch: all four relations (diagnostic: total relation time = one dispatch)
    rel_fused<<<2048, 256, 0, stream>>>(bmGG, bmCC, bmGC,
        s1gg, s2gg, s1cc, s2cc, s1gc, s2gc, s1cg, s2cg,
        gene_hT, cell_hT,
        numGG, lGG, numCC, lCC, numGC, lGC, numCG, lCG);

    // fused combine + epilogue
    combine_final<<<NG * 64 / 256, 256, 0, stream>>>(numGG, lGG, JS_GG, numGC, lGC, JS_GC,
        NG, gene_h, gamg, out_gene);
    combine_final<<<NC * 64 / 256, 256, 0, stream>>>(numCC, lCC, JS_CC, numCG, lCG, JS_CG,
        NC, cell_h, gamc, out_cell);
}